// Round 10
// baseline (172.050 us; speedup 1.0000x reference)
//
#include <hip/hip_runtime.h>

typedef __attribute__((ext_vector_type(8))) _Float16 f16x8;
typedef __attribute__((ext_vector_type(4))) float f32x4;

static constexpr int TT = 100, BB = 256, DD = 784, HH = 256;
static constexpr int MM = TT * BB;      // 25600
static constexpr int K1PAD = 800;       // 784 -> 25*32
static constexpr int N2PAD = 800;       // 784 -> 25*32 (W2 row pad)
static constexpr float MIDSC = 2048.0f, INVMID = 1.0f / 2048.0f;

__device__ __forceinline__ unsigned short f2h(float x) {
  _Float16 h = (_Float16)x;
  return *(unsigned short*)&h;
}
__device__ __forceinline__ float h2f(unsigned short u) {
  _Float16 h = *(_Float16*)&u;
  return (float)h;
}
__device__ __forceinline__ void glds16(const void* g, void* l) {
  __builtin_amdgcn_global_load_lds(
      (const __attribute__((address_space(1))) unsigned int*)g,
      (__attribute__((address_space(3))) unsigned int*)l, 16, 0, 0);
}

// Split fp32 W[N][K] into 2 f16 planes [Npad][Kpad]:
//   p0 = f16(w), p1 = f16((w - p0) * 2048); reconstruct p0 + p1/2048 (~2^-22 rel).
__global__ __launch_bounds__(256)
void split_w(const float* __restrict__ W, unsigned short* __restrict__ Ws,
             int N, int K, int Npad, int Kpad) {
  int idx = blockIdx.x * 256 + threadIdx.x;
  int total = Npad * Kpad;
  if (idx >= total) return;
  int row = idx / Kpad, col = idx - row * Kpad;
  float w = (row < N && col < K) ? W[row * K + col] : 0.0f;
  unsigned short h0 = f2h(w);
  float r = (w - h2f(h0)) * MIDSC;
  Ws[idx] = h0;
  Ws[total + idx] = f2h(r);
}

// Layer-1 GEMM: cur1[M,256] = X[M,784](binary fp32) @ (2-plane f16 W1)^T + b1.
// BM=BN=128, BK=32, 4 waves 2x2, mfma_f32_16x16x32_f16, dual plane accumulators.
// B: glds triple-buffer, counted vmcnt(4). A: reg-staged binary->f16, ds_written
// one step ahead; packA hoisted to step-top (overlaps glds issue + MFMA).
__global__ __launch_bounds__(256, 2)
void gemm1(const float* __restrict__ X, const unsigned short* __restrict__ Bs,
           const float* __restrict__ bias, float* __restrict__ C) {
  constexpr int Kpad = K1PAD, nkb = Kpad / 32;   // 25
  __shared__ unsigned short Asm[2][128 * 32];      // 16 KB
  __shared__ unsigned short Bsm[3][2][128 * 32];   // 48 KB
  const int tid = threadIdx.x;
  const int bm = blockIdx.x * 128, bn = blockIdx.y * 128;
  const int wid = tid >> 6, lane = tid & 63;
  const int wr = (wid >> 1) * 64, wc = (wid & 1) * 64;
  const int l15 = lane & 15, l4 = lane >> 4;

  f32x4 acc[2][4][4];
#pragma unroll
  for (int s = 0; s < 2; ++s)
#pragma unroll
    for (int m = 0; m < 4; ++m)
#pragma unroll
      for (int n = 0; n < 4; ++n) acc[s][m][n] = (f32x4){0.f, 0.f, 0.f, 0.f};

  const int rl = wid * 32 + (lane >> 2);
  const int ce = ((lane & 3) ^ ((lane >> 3) & 3)) * 8;
  const size_t pstr = (size_t)HH * Kpad;
  const unsigned short* bsrc0 = Bs + (size_t)(bn + rl) * Kpad + ce;
  const unsigned short* bsrc1 = Bs + (size_t)(bn + rl + 16) * Kpad + ce;

  const int rdsw = (l4 ^ ((l15 >> 1) & 3)) * 8;

  const int r0 = tid >> 2;
  const int c0log = (tid & 3) * 8;
  const int c0phys = ((tid & 3) ^ ((tid >> 3) & 3)) * 8;

  float4 aA[4], aB[4];

  auto loadA = [&](int kb, float4 (&d)[4]) {
    const int col = kb * 32 + c0log;
    const bool ok = col < DD;
    const int colc = ok ? col : 0;
    const float* p0 = &X[(size_t)(bm + r0) * DD + colc];
    const float* p1 = &X[(size_t)(bm + r0 + 64) * DD + colc];
    d[0] = *(const float4*)p0; d[1] = *(const float4*)(p0 + 4);
    d[2] = *(const float4*)p1; d[3] = *(const float4*)(p1 + 4);
    if (!ok) {
      const float4 z = make_float4(0.f, 0.f, 0.f, 0.f);
      d[0] = z; d[1] = z; d[2] = z; d[3] = z;
    }
  };
  auto packA = [&](int bi, const float4 (&s_)[4]) {
    const unsigned ONE = 0x3C00u;
    auto pk = [&](float a, float b) {
      return (a != 0.f ? ONE : 0u) | (b != 0.f ? (ONE << 16) : 0u);
    };
    uint4 v0, v1;
    v0.x = pk(s_[0].x, s_[0].y); v0.y = pk(s_[0].z, s_[0].w);
    v0.z = pk(s_[1].x, s_[1].y); v0.w = pk(s_[1].z, s_[1].w);
    v1.x = pk(s_[2].x, s_[2].y); v1.y = pk(s_[2].z, s_[2].w);
    v1.z = pk(s_[3].x, s_[3].y); v1.w = pk(s_[3].z, s_[3].w);
    *(uint4*)&Asm[bi][r0 * 32 + c0phys] = v0;
    *(uint4*)&Asm[bi][(r0 + 64) * 32 + c0phys] = v1;
  };
  auto stageB = [&](int t) {
    const int k0 = t * 32, bi = t % 3;
    glds16(bsrc0 + k0, &Bsm[bi][0][(wid * 32) * 32]);
    glds16(bsrc1 + k0, &Bsm[bi][0][(wid * 32 + 16) * 32]);
    glds16(bsrc0 + pstr + k0, &Bsm[bi][1][(wid * 32) * 32]);
    glds16(bsrc1 + pstr + k0, &Bsm[bi][1][(wid * 32 + 16) * 32]);
  };
  auto compute = [&](int kb) {
    const int cb = kb & 1, b3 = kb % 3;
    f16x8 afr[4];
#pragma unroll
    for (int m = 0; m < 4; ++m)
      afr[m] = *(const f16x8*)&Asm[cb][(wr + m * 16 + l15) * 32 + rdsw];
#pragma unroll
    for (int s = 0; s < 2; ++s) {
      f16x8 bfr[4];
#pragma unroll
      for (int n = 0; n < 4; ++n)
        bfr[n] = *(const f16x8*)&Bsm[b3][s][(wc + n * 16 + l15) * 32 + rdsw];
#pragma unroll
      for (int m = 0; m < 4; ++m)
#pragma unroll
        for (int n = 0; n < 4; ++n)
          acc[s][m][n] = __builtin_amdgcn_mfma_f32_16x16x32_f16(afr[m], bfr[n], acc[s][m][n], 0, 0, 0);
    }
  };
  auto stepK = [&](int kb, const float4 (&pk_)[4], float4 (&ld_)[4]) {
    if (kb + 1 < nkb) packA((kb + 1) & 1, pk_);
    if (kb + 2 < nkb) stageB(kb + 2);
    compute(kb);
    __builtin_amdgcn_sched_barrier(0);
    if (kb + 2 < nkb) asm volatile("s_waitcnt vmcnt(4)" ::: "memory");
    else              asm volatile("s_waitcnt vmcnt(0)" ::: "memory");
    if (kb + 2 < nkb) loadA(kb + 2, ld_);
    asm volatile("s_waitcnt lgkmcnt(0)" ::: "memory");
    __builtin_amdgcn_sched_barrier(0);
    __builtin_amdgcn_s_barrier();
    __builtin_amdgcn_sched_barrier(0);
  };

  loadA(0, aA);
  stageB(0); stageB(1);
  asm volatile("s_waitcnt vmcnt(8)" ::: "memory");
  packA(0, aA);
  loadA(1, aB);
  asm volatile("s_waitcnt vmcnt(8)" ::: "memory");
  asm volatile("s_waitcnt lgkmcnt(0)" ::: "memory");
  __builtin_amdgcn_s_barrier();
  __builtin_amdgcn_sched_barrier(0);

  for (int kb2 = 0; kb2 < nkb; kb2 += 2) {
    stepK(kb2, aB, aA);
    if (kb2 + 1 < nkb) stepK(kb2 + 1, aA, aB);
  }

#pragma unroll
  for (int m = 0; m < 4; ++m)
#pragma unroll
    for (int n = 0; n < 4; ++n) {
      const int col = bn + wc + n * 16 + l15;
      const float bv = bias[col];
#pragma unroll
      for (int r = 0; r < 4; ++r) {
        const int row = bm + wr + m * 16 + l4 * 4 + r;
        C[(size_t)row * HH + col] = fmaf(acc[1][m][n][r], INVMID, acc[0][m][n][r]) + bv;
      }
    }
}

// fp32 currents -> f16 spikes, 4 elems/thread
__global__ __launch_bounds__(256)
void lif_scan_h4(const float4* __restrict__ cur, uint2* __restrict__ spk,
                 int NE4, int nt) {
  const int tid = blockIdx.x * 256 + threadIdx.x;
  float4 mem = make_float4(0.f, 0.f, 0.f, 0.f);
  auto step1 = [](float& m, float c) {
    const float reset = (m > 1.0f) ? 1.0f : 0.0f;
    m = __fsub_rn(__fadd_rn(__fmul_rn(0.9f, m), c), reset);
    return (m > 1.0f);
  };
#pragma unroll 4
  for (int t = 0; t < nt; ++t) {
    const float4 c = cur[(size_t)t * NE4 + tid];
    unsigned s0 = step1(mem.x, c.x) ? 0x3C00u : 0u;
    unsigned s1 = step1(mem.y, c.y) ? 0x3C00u : 0u;
    unsigned s2 = step1(mem.z, c.z) ? 0x3C00u : 0u;
    unsigned s3 = step1(mem.w, c.w) ? 0x3C00u : 0u;
    uint2 o;
    o.x = s0 | (s1 << 16);
    o.y = s2 | (s3 << 16);
    spk[(size_t)t * NE4 + tid] = o;
  }
}

// Fused layer-2 GEMM + LIF, t-CHUNKED two-phase: block = 16b x 32d, 4 waves,
// chunks of 20 t. Phase 1 (GEMM): wave = (d-half, t-half) computes 10 t-slices
// (10 indep MFMA chains per ks), combines planes + bias, writes cur to LDS.
// Phase 2 (scan): all 256 threads, 2 neurons each, 20 LIF steps from LDS,
// spikes straight to d_out. 2 barriers per 20 t (vs 2 per t in r7/r9).
// LDS [b][t][d] with b-stride 644 words -> all LDS accesses <= 2-way (free).
__global__ __launch_bounds__(256, 2)
void fused_l2(const unsigned short* __restrict__ spk1,   // [100][256][256] f16
              const unsigned short* __restrict__ W2s,    // 2 planes [800][256] f16
              const float* __restrict__ b2, float* __restrict__ out) {
  constexpr int CT = 20;                  // t-chunk (100 = 5*20)
  constexpr int BST = 644;                // LDS b-row stride in words (20*32 + 4)
  __shared__ float cur2[16 * BST];        // 41.2 KB
  const int tid = threadIdx.x, wid = tid >> 6, lane = tid & 63;
  const int l15 = lane & 15, l4 = lane >> 4;
  const int bb = blockIdx.x / 25, dblk = blockIdx.x - bb * 25;   // 16 x 25
  const int b0 = bb * 16, d0 = dblk * 32;
  const int dh = wid & 1, th = wid >> 1;  // d-half, t-half
  const int dw = d0 + dh * 16;

  // W2 fragments: 2 planes x 8 k-chunks (64 VGPR), held for the whole kernel
  f16x8 wfr[2][8];
  const unsigned short* wb = W2s + (size_t)(dw + l15) * HH + l4 * 8;
#pragma unroll
  for (int s = 0; s < 2; ++s)
#pragma unroll
    for (int ks = 0; ks < 8; ++ks)
      wfr[s][ks] = *(const f16x8*)(wb + (size_t)s * (N2PAD * HH) + ks * 32);
  const int dlane = dw + l15;
  const float bv = (dlane < DD) ? b2[dlane] : 0.f;

  const unsigned short* abase = spk1 + (size_t)(b0 + l15) * HH + l4 * 8;

  // scan mapping: thread owns neurons (sb0, sd) and (sb0+8, sd)
  const int sb0 = tid >> 5, sd = tid & 31;
  const int sdg = d0 + sd;
  const bool sok = (sdg < DD);
  float mem0 = 0.f, mem1 = 0.f;
  float* op0 = out + (size_t)(b0 + sb0) * DD + sdg;
  float* op1 = out + (size_t)(b0 + 8 + sb0) * DD + sdg;

  for (int tc = 0; tc < TT; tc += CT) {
    // ---- phase 1: GEMM for t = tc + th*10 .. +9 ----
    f32x4 p0[10], p1[10];
#pragma unroll
    for (int j = 0; j < 10; ++j) {
      p0[j] = (f32x4){0.f, 0.f, 0.f, 0.f};
      p1[j] = (f32x4){0.f, 0.f, 0.f, 0.f};
    }
#pragma unroll
    for (int ks = 0; ks < 8; ++ks) {
      f16x8 a[10];
#pragma unroll
      for (int j = 0; j < 10; ++j)
        a[j] = *(const f16x8*)(abase + (size_t)(tc + th * 10 + j) * (BB * HH) + ks * 32);
#pragma unroll
      for (int j = 0; j < 10; ++j) {
        p0[j] = __builtin_amdgcn_mfma_f32_16x16x32_f16(a[j], wfr[0][ks], p0[j], 0, 0, 0);
        p1[j] = __builtin_amdgcn_mfma_f32_16x16x32_f16(a[j], wfr[1][ks], p1[j], 0, 0, 0);
      }
    }
#pragma unroll
    for (int j = 0; j < 10; ++j) {
      const int tl = th * 10 + j;
#pragma unroll
      for (int r = 0; r < 4; ++r) {
        const float c = fmaf(p1[j][r], INVMID, p0[j][r]) + bv;
        cur2[(l4 * 4 + r) * BST + tl * 32 + dh * 16 + l15] = c;
      }
    }
    __syncthreads();
    // ---- phase 2: scan 20 t, 2 neurons/thread ----
#pragma unroll
    for (int j = 0; j < CT; ++j) {
      const float c0 = cur2[sb0 * BST + j * 32 + sd];
      const float c1 = cur2[(8 + sb0) * BST + j * 32 + sd];
      const float r0 = (mem0 > 1.0f) ? 1.0f : 0.0f;
      mem0 = __fsub_rn(__fadd_rn(__fmul_rn(0.9f, mem0), c0), r0);
      const float r1 = (mem1 > 1.0f) ? 1.0f : 0.0f;
      mem1 = __fsub_rn(__fadd_rn(__fmul_rn(0.9f, mem1), c1), r1);
      if (sok) {
        const size_t to = (size_t)(tc + j) * ((size_t)BB * DD);
        op0[to] = (mem0 > 1.0f) ? 1.0f : 0.0f;
        op1[to] = (mem1 > 1.0f) ? 1.0f : 0.0f;
      }
    }
    __syncthreads();
  }
}

extern "C" void kernel_launch(void* const* d_in, const int* in_sizes, int n_in,
                              void* d_out, int out_size, void* d_ws, size_t ws_size,
                              hipStream_t stream) {
  const float* x  = (const float*)d_in[0];
  const float* W1 = (const float*)d_in[1];
  const float* b1 = (const float*)d_in[2];
  const float* W2 = (const float*)d_in[3];
  const float* b2 = (const float*)d_in[4];
  float* out = (float*)d_out;

  const size_t w1s_elems = (size_t)2 * HH * K1PAD;    // 409600
  const size_t w2s_elems = (size_t)2 * N2PAD * HH;    // 409600
  unsigned short* W1s = (unsigned short*)d_ws;
  unsigned short* W2s = W1s + w1s_elems;
  float* cur1 = (float*)(W2s + w2s_elems);
  unsigned short* spk1 = (unsigned short*)(cur1 + (size_t)MM * HH);

  dim3 blk(256);

  split_w<<<dim3((HH * K1PAD + 255) / 256), blk, 0, stream>>>(W1, W1s, HH, DD, HH, K1PAD);
  split_w<<<dim3((N2PAD * HH + 255) / 256), blk, 0, stream>>>(W2, W2s, DD, HH, N2PAD, HH);

  // layer 1: cur1[M,256] = X @ W1^T + b1
  gemm1<<<dim3(MM / 128, HH / 128), blk, 0, stream>>>(x, W1s, b1, cur1);

  // layer 1 LIF -> f16 spikes
  lif_scan_h4<<<dim3((BB * HH / 4) / 256), blk, 0, stream>>>(
      (const float4*)cur1, (uint2*)spk1, BB * HH / 4, TT);

  // layer 2 GEMM + LIF fused, t-chunked two-phase, spikes straight to d_out
  fused_l2<<<dim3(16 * 25), blk, 0, stream>>>(spk1, W2s, b2, out);
}

// Round 11
// 120.273 us; speedup vs baseline: 1.4305x; 1.4305x over previous
//
#include <hip/hip_runtime.h>

typedef __attribute__((ext_vector_type(8))) _Float16 f16x8;
typedef __attribute__((ext_vector_type(4))) float f32x4;

static constexpr int TT = 100, BB = 256, DD = 784, HH = 256;
static constexpr int MM = TT * BB;      // 25600
static constexpr int K1PAD = 800;       // 784 -> 25*32
static constexpr int N2PAD = 800;       // 784 -> 25*32 (W2 row pad)
static constexpr float MIDSC = 2048.0f, INVMID = 1.0f / 2048.0f;

__device__ __forceinline__ unsigned short f2h(float x) {
  _Float16 h = (_Float16)x;
  return *(unsigned short*)&h;
}
__device__ __forceinline__ float h2f(unsigned short u) {
  _Float16 h = *(_Float16*)&u;
  return (float)h;
}
__device__ __forceinline__ void glds16(const void* g, void* l) {
  __builtin_amdgcn_global_load_lds(
      (const __attribute__((address_space(1))) unsigned int*)g,
      (__attribute__((address_space(3))) unsigned int*)l, 16, 0, 0);
}

// Split fp32 W[N][K] into 2 f16 planes [Npad][Kpad]:
//   p0 = f16(w), p1 = f16((w - p0) * 2048); reconstruct p0 + p1/2048 (~2^-22 rel).
__global__ __launch_bounds__(256)
void split_w(const float* __restrict__ W, unsigned short* __restrict__ Ws,
             int N, int K, int Npad, int Kpad) {
  int idx = blockIdx.x * 256 + threadIdx.x;
  int total = Npad * Kpad;
  if (idx >= total) return;
  int row = idx / Kpad, col = idx - row * Kpad;
  float w = (row < N && col < K) ? W[row * K + col] : 0.0f;
  unsigned short h0 = f2h(w);
  float r = (w - h2f(h0)) * MIDSC;
  Ws[idx] = h0;
  Ws[total + idx] = f2h(r);
}

// Layer-1 GEMM: cur1[M,256] = X[M,784](binary fp32) @ (2-plane f16 W1)^T + b1.
// BM=BN=128, BK=32, 4 waves 2x2, mfma_f32_16x16x32_f16, dual plane accumulators.
// B: glds triple-buffer, counted vmcnt(4). A: reg-staged binary->f16, ds_written
// one step ahead; packA hoisted to step-top.
__global__ __launch_bounds__(256, 2)
void gemm1(const float* __restrict__ X, const unsigned short* __restrict__ Bs,
           const float* __restrict__ bias, float* __restrict__ C) {
  constexpr int Kpad = K1PAD, nkb = Kpad / 32;   // 25
  __shared__ unsigned short Asm[2][128 * 32];      // 16 KB
  __shared__ unsigned short Bsm[3][2][128 * 32];   // 48 KB
  const int tid = threadIdx.x;
  const int bm = blockIdx.x * 128, bn = blockIdx.y * 128;
  const int wid = tid >> 6, lane = tid & 63;
  const int wr = (wid >> 1) * 64, wc = (wid & 1) * 64;
  const int l15 = lane & 15, l4 = lane >> 4;

  f32x4 acc[2][4][4];
#pragma unroll
  for (int s = 0; s < 2; ++s)
#pragma unroll
    for (int m = 0; m < 4; ++m)
#pragma unroll
      for (int n = 0; n < 4; ++n) acc[s][m][n] = (f32x4){0.f, 0.f, 0.f, 0.f};

  const int rl = wid * 32 + (lane >> 2);
  const int ce = ((lane & 3) ^ ((lane >> 3) & 3)) * 8;
  const size_t pstr = (size_t)HH * Kpad;
  const unsigned short* bsrc0 = Bs + (size_t)(bn + rl) * Kpad + ce;
  const unsigned short* bsrc1 = Bs + (size_t)(bn + rl + 16) * Kpad + ce;

  const int rdsw = (l4 ^ ((l15 >> 1) & 3)) * 8;

  const int r0 = tid >> 2;
  const int c0log = (tid & 3) * 8;
  const int c0phys = ((tid & 3) ^ ((tid >> 3) & 3)) * 8;

  float4 aA[4], aB[4];

  auto loadA = [&](int kb, float4 (&d)[4]) {
    const int col = kb * 32 + c0log;
    const bool ok = col < DD;
    const int colc = ok ? col : 0;
    const float* p0 = &X[(size_t)(bm + r0) * DD + colc];
    const float* p1 = &X[(size_t)(bm + r0 + 64) * DD + colc];
    d[0] = *(const float4*)p0; d[1] = *(const float4*)(p0 + 4);
    d[2] = *(const float4*)p1; d[3] = *(const float4*)(p1 + 4);
    if (!ok) {
      const float4 z = make_float4(0.f, 0.f, 0.f, 0.f);
      d[0] = z; d[1] = z; d[2] = z; d[3] = z;
    }
  };
  auto packA = [&](int bi, const float4 (&s_)[4]) {
    const unsigned ONE = 0x3C00u;
    auto pk = [&](float a, float b) {
      return (a != 0.f ? ONE : 0u) | (b != 0.f ? (ONE << 16) : 0u);
    };
    uint4 v0, v1;
    v0.x = pk(s_[0].x, s_[0].y); v0.y = pk(s_[0].z, s_[0].w);
    v0.z = pk(s_[1].x, s_[1].y); v0.w = pk(s_[1].z, s_[1].w);
    v1.x = pk(s_[2].x, s_[2].y); v1.y = pk(s_[2].z, s_[2].w);
    v1.z = pk(s_[3].x, s_[3].y); v1.w = pk(s_[3].z, s_[3].w);
    *(uint4*)&Asm[bi][r0 * 32 + c0phys] = v0;
    *(uint4*)&Asm[bi][(r0 + 64) * 32 + c0phys] = v1;
  };
  auto stageB = [&](int t) {
    const int k0 = t * 32, bi = t % 3;
    glds16(bsrc0 + k0, &Bsm[bi][0][(wid * 32) * 32]);
    glds16(bsrc1 + k0, &Bsm[bi][0][(wid * 32 + 16) * 32]);
    glds16(bsrc0 + pstr + k0, &Bsm[bi][1][(wid * 32) * 32]);
    glds16(bsrc1 + pstr + k0, &Bsm[bi][1][(wid * 32 + 16) * 32]);
  };
  auto compute = [&](int kb) {
    const int cb = kb & 1, b3 = kb % 3;
    f16x8 afr[4];
#pragma unroll
    for (int m = 0; m < 4; ++m)
      afr[m] = *(const f16x8*)&Asm[cb][(wr + m * 16 + l15) * 32 + rdsw];
#pragma unroll
    for (int s = 0; s < 2; ++s) {
      f16x8 bfr[4];
#pragma unroll
      for (int n = 0; n < 4; ++n)
        bfr[n] = *(const f16x8*)&Bsm[b3][s][(wc + n * 16 + l15) * 32 + rdsw];
#pragma unroll
      for (int m = 0; m < 4; ++m)
#pragma unroll
        for (int n = 0; n < 4; ++n)
          acc[s][m][n] = __builtin_amdgcn_mfma_f32_16x16x32_f16(afr[m], bfr[n], acc[s][m][n], 0, 0, 0);
    }
  };
  auto stepK = [&](int kb, const float4 (&pk_)[4], float4 (&ld_)[4]) {
    if (kb + 1 < nkb) packA((kb + 1) & 1, pk_);
    if (kb + 2 < nkb) stageB(kb + 2);
    compute(kb);
    __builtin_amdgcn_sched_barrier(0);
    if (kb + 2 < nkb) asm volatile("s_waitcnt vmcnt(4)" ::: "memory");
    else              asm volatile("s_waitcnt vmcnt(0)" ::: "memory");
    if (kb + 2 < nkb) loadA(kb + 2, ld_);
    asm volatile("s_waitcnt lgkmcnt(0)" ::: "memory");
    __builtin_amdgcn_sched_barrier(0);
    __builtin_amdgcn_s_barrier();
    __builtin_amdgcn_sched_barrier(0);
  };

  loadA(0, aA);
  stageB(0); stageB(1);
  asm volatile("s_waitcnt vmcnt(8)" ::: "memory");
  packA(0, aA);
  loadA(1, aB);
  asm volatile("s_waitcnt vmcnt(8)" ::: "memory");
  asm volatile("s_waitcnt lgkmcnt(0)" ::: "memory");
  __builtin_amdgcn_s_barrier();
  __builtin_amdgcn_sched_barrier(0);

  for (int kb2 = 0; kb2 < nkb; kb2 += 2) {
    stepK(kb2, aB, aA);
    if (kb2 + 1 < nkb) stepK(kb2 + 1, aA, aB);
  }

#pragma unroll
  for (int m = 0; m < 4; ++m)
#pragma unroll
    for (int n = 0; n < 4; ++n) {
      const int col = bn + wc + n * 16 + l15;
      const float bv = bias[col];
#pragma unroll
      for (int r = 0; r < 4; ++r) {
        const int row = bm + wr + m * 16 + l4 * 4 + r;
        C[(size_t)row * HH + col] = fmaf(acc[1][m][n][r], INVMID, acc[0][m][n][r]) + bv;
      }
    }
}

// fp32 currents -> f16 spikes, 4 elems/thread
__global__ __launch_bounds__(256)
void lif_scan_h4(const float4* __restrict__ cur, uint2* __restrict__ spk,
                 int NE4, int nt) {
  const int tid = blockIdx.x * 256 + threadIdx.x;
  float4 mem = make_float4(0.f, 0.f, 0.f, 0.f);
  auto step1 = [](float& m, float c) {
    const float reset = (m > 1.0f) ? 1.0f : 0.0f;
    m = __fsub_rn(__fadd_rn(__fmul_rn(0.9f, m), c), reset);
    return (m > 1.0f);
  };
#pragma unroll 4
  for (int t = 0; t < nt; ++t) {
    const float4 c = cur[(size_t)t * NE4 + tid];
    unsigned s0 = step1(mem.x, c.x) ? 0x3C00u : 0u;
    unsigned s1 = step1(mem.y, c.y) ? 0x3C00u : 0u;
    unsigned s2 = step1(mem.z, c.z) ? 0x3C00u : 0u;
    unsigned s3 = step1(mem.w, c.w) ? 0x3C00u : 0u;
    uint2 o;
    o.x = s0 | (s1 << 16);
    o.y = s2 | (s3 << 16);
    spk[(size_t)t * NE4 + tid] = o;
  }
}

// Fused layer-2 GEMM + LIF v5: block = 16b x 32d, 2 waves (one 16-d group each).
// Per t: A t-slice (16b x 256k, 8 KB) glds-staged into LDS (triple buffer,
// 4 glds/wave, XOR-swizzled via pre-swizzled global source), 16 MFMAs (2 chains
// of 8), in-register LIF, 4 spike stores. Counted vmcnt from explicit FIFO:
//   steady (t in [1,97]): queue = [stage(t+1):4 | stores(t-1):4, stage(t+2):4,
//   stores(t):4] -> drain stage(t+1) = vmcnt(12) (st) / vmcnt(4) (pad wave).
//   t=0: no stores(-1) -> vmcnt(8)/4.  t=98: no stage(100) -> vmcnt(8)/0.
// Stores are NEVER drained mid-loop (r7's vmcnt(6) was -- its hidden serializer).
__global__ __launch_bounds__(128)
void fused_l2(const unsigned short* __restrict__ spk1,   // [100][256][256] f16
              const unsigned short* __restrict__ W2s,    // 2 planes [800][256] f16
              const float* __restrict__ b2, float* __restrict__ out) {
  __shared__ unsigned short Asm[3][16 * 256];   // 3 x 8 KB
  const int tid = threadIdx.x, wid = tid >> 6, lane = tid & 63;
  const int l15 = lane & 15, l4 = lane >> 4;
  const int bb = blockIdx.x / 25, dblk = blockIdx.x - bb * 25;  // 16b x 25d32
  const int b0 = bb * 16;
  const int d0 = dblk * 32 + wid * 16;        // this wave's 16-d column group
  const bool st = (d0 < DD);                  // wave-uniform (dblk 24, wave 1 pads)
  const int d0c = st ? d0 : 0;

  // W2 fragments: 2 planes x 8 k-chunks, in registers for the whole kernel
  f16x8 wfr[2][8];
  const unsigned short* wb = W2s + (size_t)(d0c + l15) * HH + l4 * 8;
#pragma unroll
  for (int s = 0; s < 2; ++s)
#pragma unroll
    for (int ks = 0; ks < 8; ++ks)
      wfr[s][ks] = *(const f16x8*)(wb + (size_t)s * (N2PAD * HH) + ks * 32);
  const float bv = st ? b2[d0 + l15] : 0.f;

  // glds: wave stages rows [wid*8, wid*8+8), 4 glds x 2 rows. Lane -> row
  // r = wid*8 + 2i + (lane>>5), col (lane&31)*8; source col pre-swizzled by
  // ((r&7)<<3) so the LDS (linear) ends up XOR-swizzled.
  const unsigned short* asrc[4];
#pragma unroll
  for (int i = 0; i < 4; ++i) {
    const int r = wid * 8 + 2 * i + (lane >> 5);
    const int e = ((lane & 31) * 8) ^ ((r & 7) << 3);
    asrc[i] = spk1 + (size_t)(b0 + r) * HH + e;
  }
  auto stageA = [&](int t) {
    const int bi = t % 3;
    const size_t toff = (size_t)t * (BB * HH);
#pragma unroll
    for (int i = 0; i < 4; ++i)
      glds16(asrc[i] + toff, &Asm[bi][(wid * 8 + 2 * i) * 256]);
  };

  f32x4 mem = (f32x4){0.f, 0.f, 0.f, 0.f};
  float* obase = out + (size_t)(b0 + l4 * 4) * DD + d0c + l15;

  stageA(0); stageA(1);
  // outstanding: wfr(16)+bv(<=1)+stage0(4)+stage1(4); drain through stage0
  asm volatile("s_waitcnt vmcnt(4)" ::: "memory");
  __builtin_amdgcn_s_barrier();
  __builtin_amdgcn_sched_barrier(0);

  for (int t = 0; t < TT; ++t) {
    if (t + 2 < TT) stageA(t + 2);
    const int bi = t % 3;
    f32x4 p0 = (f32x4){0.f, 0.f, 0.f, 0.f};
    f32x4 p1 = (f32x4){0.f, 0.f, 0.f, 0.f};
#pragma unroll
    for (int ks = 0; ks < 8; ++ks) {
      const f16x8 a = *(const f16x8*)&Asm[bi][l15 * 256 + ((ks * 32 + l4 * 8) ^ ((l15 & 7) << 3))];
      p0 = __builtin_amdgcn_mfma_f32_16x16x32_f16(a, wfr[0][ks], p0, 0, 0, 0);
      p1 = __builtin_amdgcn_mfma_f32_16x16x32_f16(a, wfr[1][ks], p1, 0, 0, 0);
    }
    if (st) {
      float* op = obase + (size_t)t * ((size_t)BB * DD);
#pragma unroll
      for (int r = 0; r < 4; ++r) {
        const float cur = fmaf(p1[r], INVMID, p0[r]) + bv;
        const float reset = (mem[r] > 1.0f) ? 1.0f : 0.0f;
        mem[r] = __fsub_rn(__fadd_rn(__fmul_rn(0.9f, mem[r]), cur), reset);
        op[(size_t)r * DD] = (mem[r] > 1.0f) ? 1.0f : 0.0f;
      }
    }
    __builtin_amdgcn_sched_barrier(0);
    if (t == 0) {
      // queue: [stage(1):4, stage(2):4, stores(0):4] -> drain stage(1)
      if (st) asm volatile("s_waitcnt vmcnt(8)" ::: "memory");
      else    asm volatile("s_waitcnt vmcnt(4)" ::: "memory");
    } else if (t + 2 < TT) {
      // [stage(t+1):4 | stores(t-1):4, stage(t+2):4, stores(t):4]
      if (st) asm volatile("s_waitcnt vmcnt(12)" ::: "memory");
      else    asm volatile("s_waitcnt vmcnt(4)" ::: "memory");
    } else if (t + 1 < TT) {
      // t == 98: [stage(99):4 | stores(97):4, stores(98):4]
      if (st) asm volatile("s_waitcnt vmcnt(8)" ::: "memory");
      else    asm volatile("s_waitcnt vmcnt(0)" ::: "memory");
    }
    if (t + 1 < TT) {
      __builtin_amdgcn_s_barrier();
      __builtin_amdgcn_sched_barrier(0);
    }
  }
}

extern "C" void kernel_launch(void* const* d_in, const int* in_sizes, int n_in,
                              void* d_out, int out_size, void* d_ws, size_t ws_size,
                              hipStream_t stream) {
  const float* x  = (const float*)d_in[0];
  const float* W1 = (const float*)d_in[1];
  const float* b1 = (const float*)d_in[2];
  const float* W2 = (const float*)d_in[3];
  const float* b2 = (const float*)d_in[4];
  float* out = (float*)d_out;

  const size_t w1s_elems = (size_t)2 * HH * K1PAD;    // 409600
  const size_t w2s_elems = (size_t)2 * N2PAD * HH;    // 409600
  unsigned short* W1s = (unsigned short*)d_ws;
  unsigned short* W2s = W1s + w1s_elems;
  float* cur1 = (float*)(W2s + w2s_elems);
  unsigned short* spk1 = (unsigned short*)(cur1 + (size_t)MM * HH);

  dim3 blk(256);

  split_w<<<dim3((HH * K1PAD + 255) / 256), blk, 0, stream>>>(W1, W1s, HH, DD, HH, K1PAD);
  split_w<<<dim3((N2PAD * HH + 255) / 256), blk, 0, stream>>>(W2, W2s, DD, HH, N2PAD, HH);

  // layer 1: cur1[M,256] = X @ W1^T + b1
  gemm1<<<dim3(MM / 128, HH / 128), blk, 0, stream>>>(x, W1s, b1, cur1);

  // layer 1 LIF -> f16 spikes
  lif_scan_h4<<<dim3((BB * HH / 4) / 256), blk, 0, stream>>>(
      (const float4*)cur1, (uint2*)spk1, BB * HH / 4, TT);

  // layer 2 GEMM + LIF fused, per-t glds pipeline, 400 blocks x 2 waves
  fused_l2<<<dim3(16 * 25), dim3(128), 0, stream>>>(spk1, W2s, b2, out);
}

// Round 12
// 110.149 us; speedup vs baseline: 1.5620x; 1.0919x over previous
//
#include <hip/hip_runtime.h>

typedef __attribute__((ext_vector_type(8))) _Float16 f16x8;
typedef __attribute__((ext_vector_type(4))) float f32x4;

static constexpr int TT = 100, BB = 256, DD = 784, HH = 256;
static constexpr int MM = TT * BB;      // 25600
static constexpr int K1PAD = 800;       // 784 -> 25*32
static constexpr int N2PAD = 800;       // 784 -> 25*32 (W2 row pad)
static constexpr float MIDSC = 2048.0f, INVMID = 1.0f / 2048.0f;

__device__ __forceinline__ unsigned short f2h(float x) {
  _Float16 h = (_Float16)x;
  return *(unsigned short*)&h;
}
__device__ __forceinline__ float h2f(unsigned short u) {
  _Float16 h = *(_Float16*)&u;
  return (float)h;
}
__device__ __forceinline__ void glds16(const void* g, void* l) {
  __builtin_amdgcn_global_load_lds(
      (const __attribute__((address_space(1))) unsigned int*)g,
      (__attribute__((address_space(3))) unsigned int*)l, 16, 0, 0);
}

// Split fp32 W[N][K] into 2 f16 planes [Npad][Kpad]:
//   p0 = f16(w), p1 = f16((w - p0) * 2048); reconstruct p0 + p1/2048 (~2^-22 rel).
__global__ __launch_bounds__(256)
void split_w(const float* __restrict__ W, unsigned short* __restrict__ Ws,
             int N, int K, int Npad, int Kpad) {
  int idx = blockIdx.x * 256 + threadIdx.x;
  int total = Npad * Kpad;
  if (idx >= total) return;
  int row = idx / Kpad, col = idx - row * Kpad;
  float w = (row < N && col < K) ? W[row * K + col] : 0.0f;
  unsigned short h0 = f2h(w);
  float r = (w - h2f(h0)) * MIDSC;
  Ws[idx] = h0;
  Ws[total + idx] = f2h(r);
}

// Layer-1 GEMM: cur1[M,256] = X[M,784](binary fp32) @ (2-plane f16 W1)^T + b1.
// BM=BN=128, BK=32, 4 waves 2x2, mfma_f32_16x16x32_f16, dual plane accumulators.
// B: glds triple-buffer, counted vmcnt(4). A: reg-staged binary->f16, ds_written
// one step ahead; packA hoisted to step-top.
__global__ __launch_bounds__(256, 2)
void gemm1(const float* __restrict__ X, const unsigned short* __restrict__ Bs,
           const float* __restrict__ bias, float* __restrict__ C) {
  constexpr int Kpad = K1PAD, nkb = Kpad / 32;   // 25
  __shared__ unsigned short Asm[2][128 * 32];      // 16 KB
  __shared__ unsigned short Bsm[3][2][128 * 32];   // 48 KB
  const int tid = threadIdx.x;
  const int bm = blockIdx.x * 128, bn = blockIdx.y * 128;
  const int wid = tid >> 6, lane = tid & 63;
  const int wr = (wid >> 1) * 64, wc = (wid & 1) * 64;
  const int l15 = lane & 15, l4 = lane >> 4;

  f32x4 acc[2][4][4];
#pragma unroll
  for (int s = 0; s < 2; ++s)
#pragma unroll
    for (int m = 0; m < 4; ++m)
#pragma unroll
      for (int n = 0; n < 4; ++n) acc[s][m][n] = (f32x4){0.f, 0.f, 0.f, 0.f};

  const int rl = wid * 32 + (lane >> 2);
  const int ce = ((lane & 3) ^ ((lane >> 3) & 3)) * 8;
  const size_t pstr = (size_t)HH * Kpad;
  const unsigned short* bsrc0 = Bs + (size_t)(bn + rl) * Kpad + ce;
  const unsigned short* bsrc1 = Bs + (size_t)(bn + rl + 16) * Kpad + ce;

  const int rdsw = (l4 ^ ((l15 >> 1) & 3)) * 8;

  const int r0 = tid >> 2;
  const int c0log = (tid & 3) * 8;
  const int c0phys = ((tid & 3) ^ ((tid >> 3) & 3)) * 8;

  float4 aA[4], aB[4];

  auto loadA = [&](int kb, float4 (&d)[4]) {
    const int col = kb * 32 + c0log;
    const bool ok = col < DD;
    const int colc = ok ? col : 0;
    const float* p0 = &X[(size_t)(bm + r0) * DD + colc];
    const float* p1 = &X[(size_t)(bm + r0 + 64) * DD + colc];
    d[0] = *(const float4*)p0; d[1] = *(const float4*)(p0 + 4);
    d[2] = *(const float4*)p1; d[3] = *(const float4*)(p1 + 4);
    if (!ok) {
      const float4 z = make_float4(0.f, 0.f, 0.f, 0.f);
      d[0] = z; d[1] = z; d[2] = z; d[3] = z;
    }
  };
  auto packA = [&](int bi, const float4 (&s_)[4]) {
    const unsigned ONE = 0x3C00u;
    auto pk = [&](float a, float b) {
      return (a != 0.f ? ONE : 0u) | (b != 0.f ? (ONE << 16) : 0u);
    };
    uint4 v0, v1;
    v0.x = pk(s_[0].x, s_[0].y); v0.y = pk(s_[0].z, s_[0].w);
    v0.z = pk(s_[1].x, s_[1].y); v0.w = pk(s_[1].z, s_[1].w);
    v1.x = pk(s_[2].x, s_[2].y); v1.y = pk(s_[2].z, s_[2].w);
    v1.z = pk(s_[3].x, s_[3].y); v1.w = pk(s_[3].z, s_[3].w);
    *(uint4*)&Asm[bi][r0 * 32 + c0phys] = v0;
    *(uint4*)&Asm[bi][(r0 + 64) * 32 + c0phys] = v1;
  };
  auto stageB = [&](int t) {
    const int k0 = t * 32, bi = t % 3;
    glds16(bsrc0 + k0, &Bsm[bi][0][(wid * 32) * 32]);
    glds16(bsrc1 + k0, &Bsm[bi][0][(wid * 32 + 16) * 32]);
    glds16(bsrc0 + pstr + k0, &Bsm[bi][1][(wid * 32) * 32]);
    glds16(bsrc1 + pstr + k0, &Bsm[bi][1][(wid * 32 + 16) * 32]);
  };
  auto compute = [&](int kb) {
    const int cb = kb & 1, b3 = kb % 3;
    f16x8 afr[4];
#pragma unroll
    for (int m = 0; m < 4; ++m)
      afr[m] = *(const f16x8*)&Asm[cb][(wr + m * 16 + l15) * 32 + rdsw];
#pragma unroll
    for (int s = 0; s < 2; ++s) {
      f16x8 bfr[4];
#pragma unroll
      for (int n = 0; n < 4; ++n)
        bfr[n] = *(const f16x8*)&Bsm[b3][s][(wc + n * 16 + l15) * 32 + rdsw];
#pragma unroll
      for (int m = 0; m < 4; ++m)
#pragma unroll
        for (int n = 0; n < 4; ++n)
          acc[s][m][n] = __builtin_amdgcn_mfma_f32_16x16x32_f16(afr[m], bfr[n], acc[s][m][n], 0, 0, 0);
    }
  };
  auto stepK = [&](int kb, const float4 (&pk_)[4], float4 (&ld_)[4]) {
    if (kb + 1 < nkb) packA((kb + 1) & 1, pk_);
    if (kb + 2 < nkb) stageB(kb + 2);
    compute(kb);
    __builtin_amdgcn_sched_barrier(0);
    if (kb + 2 < nkb) asm volatile("s_waitcnt vmcnt(4)" ::: "memory");
    else              asm volatile("s_waitcnt vmcnt(0)" ::: "memory");
    if (kb + 2 < nkb) loadA(kb + 2, ld_);
    asm volatile("s_waitcnt lgkmcnt(0)" ::: "memory");
    __builtin_amdgcn_sched_barrier(0);
    __builtin_amdgcn_s_barrier();
    __builtin_amdgcn_sched_barrier(0);
  };

  loadA(0, aA);
  stageB(0); stageB(1);
  asm volatile("s_waitcnt vmcnt(8)" ::: "memory");
  packA(0, aA);
  loadA(1, aB);
  asm volatile("s_waitcnt vmcnt(8)" ::: "memory");
  asm volatile("s_waitcnt lgkmcnt(0)" ::: "memory");
  __builtin_amdgcn_s_barrier();
  __builtin_amdgcn_sched_barrier(0);

  for (int kb2 = 0; kb2 < nkb; kb2 += 2) {
    stepK(kb2, aB, aA);
    if (kb2 + 1 < nkb) stepK(kb2 + 1, aA, aB);
  }

#pragma unroll
  for (int m = 0; m < 4; ++m)
#pragma unroll
    for (int n = 0; n < 4; ++n) {
      const int col = bn + wc + n * 16 + l15;
      const float bv = bias[col];
#pragma unroll
      for (int r = 0; r < 4; ++r) {
        const int row = bm + wr + m * 16 + l4 * 4 + r;
        C[(size_t)row * HH + col] = fmaf(acc[1][m][n][r], INVMID, acc[0][m][n][r]) + bv;
      }
    }
}

// fp32 currents -> f16 spikes, 4 elems/thread
__global__ __launch_bounds__(256)
void lif_scan_h4(const float4* __restrict__ cur, uint2* __restrict__ spk,
                 int NE4, int nt) {
  const int tid = blockIdx.x * 256 + threadIdx.x;
  float4 mem = make_float4(0.f, 0.f, 0.f, 0.f);
  auto step1 = [](float& m, float c) {
    const float reset = (m > 1.0f) ? 1.0f : 0.0f;
    m = __fsub_rn(__fadd_rn(__fmul_rn(0.9f, m), c), reset);
    return (m > 1.0f);
  };
#pragma unroll 4
  for (int t = 0; t < nt; ++t) {
    const float4 c = cur[(size_t)t * NE4 + tid];
    unsigned s0 = step1(mem.x, c.x) ? 0x3C00u : 0u;
    unsigned s1 = step1(mem.y, c.y) ? 0x3C00u : 0u;
    unsigned s2 = step1(mem.z, c.z) ? 0x3C00u : 0u;
    unsigned s3 = step1(mem.w, c.w) ? 0x3C00u : 0u;
    uint2 o;
    o.x = s0 | (s1 << 16);
    o.y = s2 | (s3 << 16);
    spk[(size_t)t * NE4 + tid] = o;
  }
}

// Fused layer-2 GEMM + LIF v6: ONE WAVE per block, 16b x 16d tile, all 100 t.
// Zero barriers (single wave -> pure counted-vmcnt ordering). A t-slice (8 KB)
// glds-staged into a 4-deep LDS ring; stores NEVER drained mid-loop.
// FIFO at the wait point of iteration t (issue order):
//   [stores(t-2):4, stage(t+1):8, stores(t-1):4, stage(t+2):8] = 24
//   -> vmcnt(24) drains stage(t) (and stores(t-3)-). Prologue drains all once.
//   t=98 (no stage(100)): queue [st(95):4,sg(98):8,st(96):4,sg(99):8,st(97):4]=28
//   -> vmcnt(16). t=99: [st(96):4,sg(99):8,st(97):4,st(98):4]=20 -> vmcnt(8).
// MFMA: 4 independent chains of 4 (p0a/p0b/p1a/p1b) to halve dep-chain latency.
__global__ __launch_bounds__(64)
void fused_l2(const unsigned short* __restrict__ spk1,   // [100][256][256] f16
              const unsigned short* __restrict__ W2s,    // 2 planes [800][256] f16
              const float* __restrict__ b2, float* __restrict__ out) {
  __shared__ unsigned short Asm[4][16 * 256];   // 32 KB ring
  const int lane = threadIdx.x;                  // 64
  const int l15 = lane & 15, l4 = lane >> 4;
  const int bb = blockIdx.x / 49, dd = blockIdx.x - bb * 49;  // 16 x 49, no tail
  const int b0 = bb * 16, d0 = dd * 16;

  // glds: instr i covers rows 2i, 2i+1; lane -> row 2i + (lane>>5),
  // col (lane&31)*8 pre-swizzled by ^((r&7)<<3) -> LDS ends up XOR-swizzled.
  const unsigned short* asrc[8];
#pragma unroll
  for (int i = 0; i < 8; ++i) {
    const int r = 2 * i + (lane >> 5);
    const int e = ((lane & 31) * 8) ^ ((r & 7) << 3);
    asrc[i] = spk1 + (size_t)(b0 + r) * HH + e;
  }
  auto stageA = [&](int t) {
    const size_t toff = (size_t)t * (BB * HH);
    unsigned short* dst = &Asm[t & 3][0];
#pragma unroll
    for (int i = 0; i < 8; ++i)
      glds16(asrc[i] + toff, dst + 2 * i * 256);
  };

  stageA(0);
  stageA(1);

  // W2 fragments: 2 planes x 8 k-chunks, registers for the whole kernel
  f16x8 wfr[2][8];
  const unsigned short* wb = W2s + (size_t)(d0 + l15) * HH + l4 * 8;
#pragma unroll
  for (int s = 0; s < 2; ++s)
#pragma unroll
    for (int ks = 0; ks < 8; ++ks)
      wfr[s][ks] = *(const f16x8*)(wb + (size_t)s * (N2PAD * HH) + ks * 32);
  const float bv = b2[d0 + l15];

  // prologue: drain everything once (wfr + bias + stage(0) + stage(1))
  asm volatile("s_waitcnt vmcnt(0)" ::: "memory");
  __builtin_amdgcn_sched_barrier(0);

  f32x4 mem = (f32x4){0.f, 0.f, 0.f, 0.f};
  float* obase = out + (size_t)(b0 + l4 * 4) * DD + d0 + l15;

  for (int t = 0; t < TT; ++t) {
    if (t + 2 < TT) stageA(t + 2);
    // counted wait: ensure stage(t) landed, keep stage(t+1/t+2) + stores flying
    if (t >= 2) {
      if (t <= 97)      asm volatile("s_waitcnt vmcnt(24)" ::: "memory");
      else if (t == 98) asm volatile("s_waitcnt vmcnt(16)" ::: "memory");
      else              asm volatile("s_waitcnt vmcnt(8)" ::: "memory");
    }
    __builtin_amdgcn_sched_barrier(0);

    const unsigned short* abuf = &Asm[t & 3][0];
    f32x4 p0a = (f32x4){0.f, 0.f, 0.f, 0.f}, p0b = p0a, p1a = p0a, p1b = p0a;
#pragma unroll
    for (int ks = 0; ks < 4; ++ks) {
      const f16x8 a = *(const f16x8*)&abuf[l15 * 256 + ((ks * 32 + l4 * 8) ^ ((l15 & 7) << 3))];
      p0a = __builtin_amdgcn_mfma_f32_16x16x32_f16(a, wfr[0][ks], p0a, 0, 0, 0);
      p1a = __builtin_amdgcn_mfma_f32_16x16x32_f16(a, wfr[1][ks], p1a, 0, 0, 0);
    }
#pragma unroll
    for (int ks = 4; ks < 8; ++ks) {
      const f16x8 a = *(const f16x8*)&abuf[l15 * 256 + ((ks * 32 + l4 * 8) ^ ((l15 & 7) << 3))];
      p0b = __builtin_amdgcn_mfma_f32_16x16x32_f16(a, wfr[0][ks], p0b, 0, 0, 0);
      p1b = __builtin_amdgcn_mfma_f32_16x16x32_f16(a, wfr[1][ks], p1b, 0, 0, 0);
    }

    float* op = obase + (size_t)t * ((size_t)BB * DD);
#pragma unroll
    for (int r = 0; r < 4; ++r) {
      const float p0 = p0a[r] + p0b[r];
      const float p1 = p1a[r] + p1b[r];
      const float cur = fmaf(p1, INVMID, p0) + bv;
      const float reset = (mem[r] > 1.0f) ? 1.0f : 0.0f;
      mem[r] = __fsub_rn(__fadd_rn(__fmul_rn(0.9f, mem[r]), cur), reset);
      op[(size_t)r * DD] = (mem[r] > 1.0f) ? 1.0f : 0.0f;
    }
  }
}

extern "C" void kernel_launch(void* const* d_in, const int* in_sizes, int n_in,
                              void* d_out, int out_size, void* d_ws, size_t ws_size,
                              hipStream_t stream) {
  const float* x  = (const float*)d_in[0];
  const float* W1 = (const float*)d_in[1];
  const float* b1 = (const float*)d_in[2];
  const float* W2 = (const float*)d_in[3];
  const float* b2 = (const float*)d_in[4];
  float* out = (float*)d_out;

  const size_t w1s_elems = (size_t)2 * HH * K1PAD;    // 409600
  const size_t w2s_elems = (size_t)2 * N2PAD * HH;    // 409600
  unsigned short* W1s = (unsigned short*)d_ws;
  unsigned short* W2s = W1s + w1s_elems;
  float* cur1 = (float*)(W2s + w2s_elems);
  unsigned short* spk1 = (unsigned short*)(cur1 + (size_t)MM * HH);

  dim3 blk(256);

  split_w<<<dim3((HH * K1PAD + 255) / 256), blk, 0, stream>>>(W1, W1s, HH, DD, HH, K1PAD);
  split_w<<<dim3((N2PAD * HH + 255) / 256), blk, 0, stream>>>(W2, W2s, DD, HH, N2PAD, HH);

  // layer 1: cur1[M,256] = X @ W1^T + b1
  gemm1<<<dim3(MM / 128, HH / 128), blk, 0, stream>>>(x, W1s, b1, cur1);

  // layer 1 LIF -> f16 spikes
  lif_scan_h4<<<dim3((BB * HH / 4) / 256), blk, 0, stream>>>(
      (const float4*)cur1, (uint2*)spk1, BB * HH / 4, TT);

  // layer 2 GEMM + LIF fused: 784 single-wave blocks, zero barriers
  fused_l2<<<dim3(16 * 49), dim3(64), 0, stream>>>(spk1, W2s, b2, out);
}